// Round 3
// baseline (594.641 us; speedup 1.0000x reference)
//
#include <hip/hip_runtime.h>
#include <cstddef>

#define NPIX 1024   // H*W = 32*32

// ---------------------------------------------------------------------------
// Workspace layout (float offsets). Pool = 37,748,736 floats = 151.0 MB.
//   [0        , 12582912)  qkv   (B x 768 x 1024)     -- phase A
//   [12582912 , 25165824)  dpw   (B x 768 x 1024)     -- phase A
//   [25165824 , 33554432)  att   (B x 512 x 1024)     -- phase A
//   [33554432 , 37748736)  t1    (B x 256 x 1024)     -- live through both phases
//        kvp (2048 x 1056 = 2.16M floats) aliases t1: dead before proj writes t1
//   [0        , 16777216)  h1    (B x 1024 x 1024)    -- phase B
//   [16777216 , 33554432)  h2    (B x 1024 x 1024)    -- phase B
// ---------------------------------------------------------------------------
static constexpr size_t QKV_OFF = 0;
static constexpr size_t DPW_OFF = 12582912;
static constexpr size_t ATT_OFF = 25165824;
static constexpr size_t T1_OFF  = 33554432;
static constexpr size_t H1_OFF  = 0;
static constexpr size_t H2_OFF  = 16777216;

typedef __attribute__((ext_vector_type(8))) short bf16x8;
typedef __attribute__((ext_vector_type(4))) float f32x4;

__device__ inline unsigned short f2bf(float f) {
    union { float f; unsigned int u; } v; v.f = f;
    unsigned int u = v.u;
    u += 0x7FFFu + ((u >> 16) & 1u);        // round-to-nearest-even
    return (unsigned short)(u >> 16);
}
__device__ inline unsigned int pk2(float a, float b) {
    return (unsigned int)f2bf(a) | ((unsigned int)f2bf(b) << 16);
}
__device__ inline int swz(int row) { return (row ^ (row >> 3)) & 3; }

// ---------------------------------------------------------------------------
// MFMA GEMM: Y[b,o,n] = sum_c W[o,c] * X[b,c,n]  (+ fused epilogue).
// Block tile BM x 128 (BM = 128 or 64), 4 waves (2x2).
//   BM=128: wave 64x64 (4x4 frags);  BM=64: wave 32x64 (2x4 frags).
// LDS rows = 40 ushort (80B: b128 stays 16B-aligned) + 16B-slot XOR swizzle
//   slot ^= (row ^ row>>3) & 3  on BOTH write and read -> <=2-way banks (free).
// Register prefetch: next K-tile global loads issued between frag reads and
// MFMA; packed + written to LDS after the post-MFMA barrier.
// EPI: 0 = plain, 1 = BN + residual (+ACC), 2 = bias + hswish.
// ---------------------------------------------------------------------------
template<int BM, int EPI, bool ACC>
__global__ __launch_bounds__(256)
void gemm_bf16(const float* __restrict__ X, const float* __restrict__ W,
               float* __restrict__ Y, const int O, const int K,
               const float* __restrict__ res,
               const float* __restrict__ bng, const float* __restrict__ bnb,
               const float* __restrict__ bnm, const float* __restrict__ bnv,
               const float* __restrict__ bias)
{
    constexpr int APASS = BM / 64;
    constexpr int WM    = (BM == 128) ? 64 : 32;
    constexpr int MI    = WM / 16;

    __shared__ unsigned short As[BM][40];
    __shared__ unsigned short Bs[128][40];

    const int t    = threadIdx.x;
    const int lane = t & 63;
    const int w    = t >> 6;
    const int o0   = blockIdx.x * BM;
    const int b    = blockIdx.y >> 3;
    const int n0   = (blockIdx.y & 7) * 128;

    const int wo = (w >> 1) * WM;
    const int wn = (w & 1) * 64;

    f32x4 acc[MI][4];
#pragma unroll
    for (int i = 0; i < MI; i++)
#pragma unroll
        for (int j = 0; j < 4; j++) {
            f32x4 z = {0.f, 0.f, 0.f, 0.f};
            acc[i][j] = z;
        }

    // staging maps
    const int ao    = t >> 2;        // A row 0..63 (+64 per pass)
    const int aslot = t & 3;         // A logical 16B k-slot
    const int bn    = t & 63;        // B rows bn, bn+64
    const int bslot = t >> 6;        // B logical 16B k-slot

    const float* Wb = W + (size_t)(o0 + ao) * K + aslot * 8;
    const float* Xb = X + (size_t)b * K * NPIX + n0 + bn;

    float fa[APASS][8];
    float fb[2][8];

    auto loadT = [&](int k0) {
#pragma unroll
        for (int p = 0; p < APASS; p++) {
            const float4 u = *(const float4*)(Wb + (size_t)p * 64 * K + k0);
            const float4 v = *(const float4*)(Wb + (size_t)p * 64 * K + k0 + 4);
            fa[p][0] = u.x; fa[p][1] = u.y; fa[p][2] = u.z; fa[p][3] = u.w;
            fa[p][4] = v.x; fa[p][5] = v.y; fa[p][6] = v.z; fa[p][7] = v.w;
        }
#pragma unroll
        for (int j = 0; j < 8; j++) {
            const float* xp = Xb + (size_t)(k0 + bslot * 8 + j) * NPIX;
            fb[0][j] = xp[0];
            fb[1][j] = xp[64];
        }
    };

    auto storeT = [&]() {
#pragma unroll
        for (int p = 0; p < APASS; p++) {
            const int row = ao + p * 64;
            uint4 c;
            c.x = pk2(fa[p][0], fa[p][1]); c.y = pk2(fa[p][2], fa[p][3]);
            c.z = pk2(fa[p][4], fa[p][5]); c.w = pk2(fa[p][6], fa[p][7]);
            *(uint4*)(&As[row][(aslot ^ swz(row)) * 8]) = c;
        }
#pragma unroll
        for (int s = 0; s < 2; s++) {
            const int row = bn + s * 64;
            uint4 c;
            c.x = pk2(fb[s][0], fb[s][1]); c.y = pk2(fb[s][2], fb[s][3]);
            c.z = pk2(fb[s][4], fb[s][5]); c.w = pk2(fb[s][6], fb[s][7]);
            *(uint4*)(&Bs[row][(bslot ^ swz(row)) * 8]) = c;
        }
    };

    const int l16 = lane & 15;
    const int lq  = lane >> 4;

    loadT(0);
    storeT();

    for (int k0 = 0; k0 < K; k0 += 32) {
        __syncthreads();
        bf16x8 afr[MI], bfr[4];
#pragma unroll
        for (int i = 0; i < MI; i++) {
            const int row = wo + i * 16 + l16;
            afr[i] = *(const bf16x8*)(&As[row][(lq ^ swz(row)) * 8]);
        }
#pragma unroll
        for (int j = 0; j < 4; j++) {
            const int row = wn + j * 16 + l16;
            bfr[j] = *(const bf16x8*)(&Bs[row][(lq ^ swz(row)) * 8]);
        }
        const bool more = (k0 + 32 < K);
        if (more) loadT(k0 + 32);          // overlap with MFMA below
#pragma unroll
        for (int i = 0; i < MI; i++)
#pragma unroll
            for (int j = 0; j < 4; j++)
                acc[i][j] = __builtin_amdgcn_mfma_f32_16x16x32_bf16(
                    afr[i], bfr[j], acc[i][j], 0, 0, 0);
        if (more) {
            __syncthreads();
            storeT();
        }
    }

    // ---- epilogue. C/D layout: col = lane&15, row = (lane>>4)*4 + reg.
    const int r0 = lq * 4;
    float scale[MI][4], shift[MI][4];
    if (EPI == 1) {
#pragma unroll
        for (int i = 0; i < MI; i++)
#pragma unroll
            for (int r = 0; r < 4; r++) {
                const int o = o0 + wo + i * 16 + r0 + r;
                const float inv = bng[o] / sqrtf(bnv[o] + 1e-5f);
                scale[i][r] = inv;
                shift[i][r] = bnb[o] - bnm[o] * inv;
            }
    } else if (EPI == 2) {
#pragma unroll
        for (int i = 0; i < MI; i++)
#pragma unroll
            for (int r = 0; r < 4; r++)
                shift[i][r] = bias[o0 + wo + i * 16 + r0 + r];
    }
#pragma unroll
    for (int i = 0; i < MI; i++) {
#pragma unroll
        for (int j = 0; j < 4; j++) {
            const int nn = n0 + wn + j * 16 + l16;
            const size_t base = ((size_t)b * O + o0 + wo + i * 16 + r0) * NPIX + nn;
#pragma unroll
            for (int r = 0; r < 4; r++) {
                const size_t off = base + (size_t)r * NPIX;
                float v = acc[i][j][r];
                if (EPI == 1) {
                    v = v * scale[i][r] + shift[i][r] + res[off];
                } else if (EPI == 2) {
                    v += shift[i][r];
                    v = v * fminf(fmaxf(v + 3.f, 0.f), 6.f) * (1.f / 6.f);
                }
                if (ACC) v += Y[off];
                Y[off] = v;
            }
        }
    }
}

// ---------------------------------------------------------------------------
// Depthwise 5x5 SAME, one (b,c) 32x32 plane per block.
// ---------------------------------------------------------------------------
__global__ __launch_bounds__(256)
void dwconv5x5(const float* __restrict__ X, const float* __restrict__ Wd,
               float* __restrict__ Y)
{
    __shared__ float tile[36 * 36];
    __shared__ float wl[25];
    const int t  = threadIdx.x;
    const int bc = blockIdx.x;            // b*768 + c
    const int c  = bc % 768;
    const float* xp = X + (size_t)bc * NPIX;
    if (t < 25) wl[t] = Wd[c * 25 + t];
    for (int i = t; i < 36 * 36; i += 256) {
        const int r = i / 36 - 2;
        const int q = i % 36 - 2;
        tile[i] = (r >= 0 && r < 32 && q >= 0 && q < 32) ? xp[r * 32 + q] : 0.f;
    }
    __syncthreads();
#pragma unroll
    for (int p = 0; p < 4; p++) {
        const int px = t + p * 256;
        const int h = px >> 5, w = px & 31;
        float s = 0.f;
#pragma unroll
        for (int ky = 0; ky < 5; ky++)
#pragma unroll
            for (int kx = 0; kx < 5; kx++)
                s = fmaf(tile[(h + ky) * 36 + (w + kx)], wl[ky * 5 + kx], s);
        Y[(size_t)bc * NPIX + px] = s;
    }
}

// ---------------------------------------------------------------------------
// Depthwise 3x3 SAME + bias + hswish, one (b,c) plane per block.
// ---------------------------------------------------------------------------
__global__ __launch_bounds__(256)
void dwconv3x3_hsw(const float* __restrict__ X, const float* __restrict__ Wd,
                   const float* __restrict__ bias, float* __restrict__ Y)
{
    __shared__ float tile[34 * 34];
    __shared__ float wl[9];
    const int t  = threadIdx.x;
    const int bc = blockIdx.x;            // b*1024 + c
    const int c  = bc & 1023;
    const float* xp = X + (size_t)bc * NPIX;
    if (t < 9) wl[t] = Wd[c * 9 + t];
    const float bb = bias[c];
    for (int i = t; i < 34 * 34; i += 256) {
        const int r = i / 34 - 1;
        const int q = i % 34 - 1;
        tile[i] = (r >= 0 && r < 32 && q >= 0 && q < 32) ? xp[r * 32 + q] : 0.f;
    }
    __syncthreads();
#pragma unroll
    for (int p = 0; p < 4; p++) {
        const int px = t + p * 256;
        const int h = px >> 5, w = px & 31;
        float s = bb;
#pragma unroll
        for (int ky = 0; ky < 3; ky++)
#pragma unroll
            for (int kx = 0; kx < 3; kx++)
                s = fmaf(tile[(h + ky) * 34 + (w + kx)], wl[ky * 3 + kx], s);
        s = s * fminf(fmaxf(s + 3.f, 0.f), 6.f) * (1.f / 6.f);
        Y[(size_t)bc * NPIX + px] = s;
    }
}

// ---------------------------------------------------------------------------
// Grouped 32->32 1x1 (24 groups), in-place on D.
// ---------------------------------------------------------------------------
__global__ __launch_bounds__(256)
void grouped_pw(float* __restrict__ D, const float* __restrict__ Wg)
{
    __shared__ float ws[1024];
    const int t     = threadIdx.x;
    const int blk   = blockIdx.x;          // (b*24+g)*4 + chunk
    const int chunk = blk & 3;
    const int bg    = blk >> 2;
    const int g     = bg % 24;
    const int b     = bg / 24;
    for (int i = t; i < 1024; i += 256) ws[i] = Wg[g * 1024 + i];
    __syncthreads();
    const int px = chunk * 256 + t;
    float* dp = D + ((size_t)(b * 768 + g * 32)) * NPIX + px;
    float in[32];
#pragma unroll
    for (int i = 0; i < 32; i++) in[i] = dp[(size_t)i * NPIX];
#pragma unroll
    for (int o = 0; o < 32; o++) {
        float s = 0.f;
#pragma unroll
        for (int i = 0; i < 32; i++) s = fmaf(ws[o * 32 + i], in[i], s);
        dp[(size_t)o * NPIX] = s;
    }
}

// ---------------------------------------------------------------------------
// Attention phase 1: partial kv[33][32] per (b,h,chunk-of-128-pixels).
// ---------------------------------------------------------------------------
__global__ __launch_bounds__(256)
void attn_kv_partial(const float* __restrict__ qkv, const float* __restrict__ dpw,
                     float* __restrict__ kvp)
{
    __shared__ float Ks[32][130];
    __shared__ float Vs[32][130];
    const int t   = threadIdx.x;
    const int blk = blockIdx.x;           // bh*8 + ch
    const int ch  = blk & 7;
    const int bh  = blk >> 3;
    const int b   = bh >> 4;
    const int h   = bh & 15;
    const float* base = (h < 8)
        ? qkv + ((size_t)(b * 768 + h * 96)) * NPIX
        : dpw + ((size_t)(b * 768 + (h - 8) * 96)) * NPIX;
    const float* kp = base + 32 * NPIX + ch * 128;
    const float* vp = base + 64 * NPIX + ch * 128;
    const int srow = t >> 3;              // 0..31
    const int scol = (t & 7) * 16;        // 0..112
#pragma unroll
    for (int j = 0; j < 16; j += 2) {
        float2 kk = *(const float2*)(kp + (size_t)srow * NPIX + scol + j);
        kk.x = fmaxf(kk.x, 0.f);
        kk.y = fmaxf(kk.y, 0.f);
        *(float2*)(&Ks[srow][scol + j]) = kk;
        *(float2*)(&Vs[srow][scol + j]) =
            *(const float2*)(vp + (size_t)srow * NPIX + scol + j);
    }
    __syncthreads();
    float* outp = kvp + (size_t)blk * 1056;
#pragma unroll
    for (int i = 0; i < 4; i++) {
        const int p = t + i * 256;
        const int d = p >> 5;
        const int e = p & 31;
        float a = 0.f;
        for (int nn = 0; nn < 128; nn += 2) {
            const float2 kk = *(const float2*)(&Ks[e][nn]);
            const float2 vv = *(const float2*)(&Vs[d][nn]);
            a = fmaf(vv.x, kk.x, a);
            a = fmaf(vv.y, kk.y, a);
        }
        outp[p] = a;
    }
    if (t < 32) {
        float a = 0.f;
        for (int nn = 0; nn < 128; nn += 2) {
            const float2 kk = *(const float2*)(&Ks[t][nn]);
            a += kk.x + kk.y;
        }
        outp[1024 + t] = a;
    }
}

// ---------------------------------------------------------------------------
// Attention phase 2: reduce kv partials (LDS), then per-pixel apply.
// ---------------------------------------------------------------------------
__global__ __launch_bounds__(256)
void attn_apply(const float* __restrict__ qkv, const float* __restrict__ dpw,
                const float* __restrict__ kvp, float* __restrict__ att)
{
    __shared__ float kvs[1056];
    const int t   = threadIdx.x;
    const int blk = blockIdx.x;           // bh*4 + qc
    const int qc  = blk & 3;
    const int bh  = blk >> 2;
    const int b   = bh >> 4;
    const int h   = bh & 15;
    for (int idx = t; idx < 1056; idx += 256) {
        float s = 0.f;
#pragma unroll
        for (int ch = 0; ch < 8; ch++)
            s += kvp[((size_t)bh * 8 + ch) * 1056 + idx];
        kvs[idx] = s;
    }
    __syncthreads();
    const float* qp = (h < 8)
        ? qkv + ((size_t)(b * 768 + h * 96)) * NPIX
        : dpw + ((size_t)(b * 768 + (h - 8) * 96)) * NPIX;
    const int n = qc * 256 + t;
    float q[32];
#pragma unroll
    for (int e = 0; e < 32; e++) q[e] = fmaxf(qp[(size_t)e * NPIX + n], 0.f);
    float den = 0.f;
#pragma unroll
    for (int e = 0; e < 32; e++) den = fmaf(kvs[1024 + e], q[e], den);
    const float inv = 1.f / (den + 1e-15f);
    float* op = att + ((size_t)(b * 512 + h * 32)) * NPIX + n;
    for (int d = 0; d < 32; d++) {
        float a = 0.f;
#pragma unroll
        for (int e = 0; e < 32; e++) a = fmaf(kvs[d * 32 + e], q[e], a);
        op[(size_t)d * NPIX] = a * inv;
    }
}

// ---------------------------------------------------------------------------
extern "C" void kernel_launch(void* const* d_in, const int* in_sizes, int n_in,
                              void* d_out, int out_size, void* d_ws, size_t ws_size,
                              hipStream_t stream)
{
    (void)in_sizes; (void)n_in; (void)out_size; (void)ws_size;

    const float* x      = (const float*)d_in[0];
    const float* y      = (const float*)d_in[1];
    const float* qkv_w  = (const float*)d_in[2];
    const float* dw5_w  = (const float*)d_in[3];
    const float* pwg_w  = (const float*)d_in[4];
    const float* proj_w = (const float*)d_in[5];
    const float* proj_g = (const float*)d_in[6];
    const float* proj_b = (const float*)d_in[7];
    const float* proj_m = (const float*)d_in[8];
    const float* proj_v = (const float*)d_in[9];
    const float* inv_w  = (const float*)d_in[10];
    const float* inv_b  = (const float*)d_in[11];
    const float* dwc_w  = (const float*)d_in[12];
    const float* dwc_b  = (const float*)d_in[13];
    const float* pw_w   = (const float*)d_in[14];
    const float* pw_g   = (const float*)d_in[15];
    const float* pw_b   = (const float*)d_in[16];
    const float* pw_m   = (const float*)d_in[17];
    const float* pw_v   = (const float*)d_in[18];

    float* ws   = (float*)d_ws;
    float* wqkv = ws + QKV_OFF;
    float* wdpw = ws + DPW_OFF;
    float* watt = ws + ATT_OFF;
    float* wt1  = ws + T1_OFF;
    float* wkvp = ws + T1_OFF;    // aliases t1 (dead until proj writes it)
    float* wh1  = ws + H1_OFF;
    float* wh2  = ws + H2_OFF;
    float* out  = (float*)d_out;

    for (int blk = 0; blk < 2; blk++) {
        const float* t = (blk == 0) ? x : y;

        // --- lite_mla ---
        gemm_bf16<128, 0, false><<<dim3(6, 128), 256, 0, stream>>>(
            t, qkv_w, wqkv, 768, 256,
            nullptr, nullptr, nullptr, nullptr, nullptr, nullptr);
        dwconv5x5<<<dim3(12288), 256, 0, stream>>>(wqkv, dw5_w, wdpw);
        grouped_pw<<<dim3(1536), 256, 0, stream>>>(wdpw, pwg_w);
        attn_kv_partial<<<dim3(2048), 256, 0, stream>>>(wqkv, wdpw, wkvp);
        attn_apply<<<dim3(1024), 256, 0, stream>>>(wqkv, wdpw, wkvp, watt);
        gemm_bf16<64, 1, false><<<dim3(4, 128), 256, 0, stream>>>(
            watt, proj_w, wt1, 256, 512,
            t, proj_g, proj_b, proj_m, proj_v, nullptr);

        // --- mbconv ---
        gemm_bf16<128, 2, false><<<dim3(8, 128), 256, 0, stream>>>(
            wt1, inv_w, wh1, 1024, 256,
            nullptr, nullptr, nullptr, nullptr, nullptr, inv_b);
        dwconv3x3_hsw<<<dim3(16384), 256, 0, stream>>>(wh1, dwc_w, dwc_b, wh2);
        if (blk == 0) {
            gemm_bf16<64, 1, false><<<dim3(4, 128), 256, 0, stream>>>(
                wh2, pw_w, out, 256, 1024,
                wt1, pw_g, pw_b, pw_m, pw_v, nullptr);
        } else {
            gemm_bf16<64, 1, true><<<dim3(4, 128), 256, 0, stream>>>(
                wh2, pw_w, out, 256, 1024,
                wt1, pw_g, pw_b, pw_m, pw_v, nullptr);
        }
    }
}